// Round 12
// baseline (629.599 us; speedup 1.0000x reference)
//
#include <hip/hip_runtime.h>
#include <hip/hip_bf16.h>

#ifndef BN_EPS
#define BN_EPS 1e-5f
#endif

// ---------------------------------------------------------------------------
// N=100000, C=64, E=1600000.
// R12: node-count fusion (R11 post-mortem: kernels sum ~150-170us, ~8us/node
// serialization gap x 8 nodes). Graph = 4 nodes:
//   memset(4.2KB) -> k_build(pre+scan+sub+csr, software grid barriers)
//   -> k_agg (unchanged, 2048 blocks, occupancy-sensitive)
//   -> k_tail (gemm-stats + barrier + BN+ReLU out, LDS tile reused).
// Software barrier: device-scope atomic counter + acquire spin; correct
// because __syncthreads drains vmcnt (stores complete) before arrival, and
// cross-phase buffers use agent-scope (sc1) stores -> coherent point, since
// per-XCD L2s are NOT coherent within a single kernel.
// Co-residency: k_build 832 blocks @24.8KB LDS -> 6 blocks/CU cap = 1536.
//               k_tail 391 blocks @34.8KB LDS -> >=2 blocks/CU cap = 512+.
// bias cancels inside BatchNorm, skipped.
// ---------------------------------------------------------------------------

#define NPB 8192
#define NPB_SHIFT 13
#define BUILD_GRID 832

__device__ __forceinline__ unsigned short f2bf(float f) {
    unsigned u = __float_as_uint(f);
    u += 0x7FFF + ((u >> 16) & 1);  // round-to-nearest-even
    return (unsigned short)(u >> 16);
}
__device__ __forceinline__ float bf2f(unsigned v) {
    return __uint_as_float(v << 16);
}

// Grid barrier: requires all blocks co-resident. __syncthreads drains vmcnt
// (all prior stores/atomics complete) before the arrive-add.
__device__ __forceinline__ void gbar(int* ctr, int nb) {
    __syncthreads();
    if (threadIdx.x == 0) {
        __hip_atomic_fetch_add(ctr, 1, __ATOMIC_ACQ_REL, __HIP_MEMORY_SCOPE_AGENT);
        while (__hip_atomic_load(ctr, __ATOMIC_ACQUIRE, __HIP_MEMORY_SCOPE_AGENT) < nb)
            __builtin_amdgcn_s_sleep(2);
    }
    __syncthreads();
}

// Agent-scope stores: push to the cross-XCD coherent point.
__device__ __forceinline__ void st_agent_u(unsigned* p, unsigned v) {
    __hip_atomic_store(p, v, __ATOMIC_RELAXED, __HIP_MEMORY_SCOPE_AGENT);
}
__device__ __forceinline__ void st_agent_i(int* p, int v) {
    __hip_atomic_store(p, v, __ATOMIC_RELAXED, __HIP_MEMORY_SCOPE_AGENT);
}

struct PreS { int hist[16], hexcl[16], hcur[16], gbase[16]; int h2[1024];
              unsigned lout[4096]; unsigned char lb[4096]; };
struct ScanS { int part[256]; };
struct SubS { int hist[64], hexcl[64], hcur[64], gbase[64];
              unsigned lout[4096]; unsigned char lb[4096]; };
struct CsrS { int hist[128], lbase[128], lcur[128]; };
union BuildSm { PreS pre; ScanS scan; SubS sub; CsrS csr; };

// Phases: 0 coarse bin (slack regions, scan-free) + subbucket hist + x->bf16;
// 1 block0 scans cnt2 -> sbase/scur (+zero stats); 2 sub sort; 3 csr build.
__global__ __launch_bounds__(256) void k_build(
    const float* __restrict__ x, const int* __restrict__ src,
    const int* __restrict__ dst, unsigned short* __restrict__ xb,
    int* cnt2, int* bcnt, unsigned* binned, int* sbase, int* scur,
    float* stats, int* deg, float* dinv, int* offs, int* csr,
    unsigned* sorted2, int* ctrs,
    int E, int n4, int SUBTOT, int cap, int B, int N) {
    __shared__ BuildSm sm;
    int tid = threadIdx.x;
    int nchunk = (E + 4095) / 4096;

    // ---- phase 0 ----
    for (int c = blockIdx.x; c < nchunk; c += gridDim.x) {
        int c0 = c * 4096;
        int cnt = min(4096, E - c0);
        if (tid < 16) sm.pre.hist[tid] = 0;
        for (int i = tid; i < SUBTOT; i += 256) sm.pre.h2[i] = 0;
        __syncthreads();
        for (int i = tid; i < cnt; i += 256) {
            int d = dst[c0 + i];
            atomicAdd(&sm.pre.hist[d >> NPB_SHIFT], 1);
            atomicAdd(&sm.pre.h2[d >> 7], 1);
        }
        __syncthreads();
        if (tid == 0) {
            int acc = 0;
            for (int b = 0; b < 16; b++) {
                sm.pre.hexcl[b] = acc; sm.pre.hcur[b] = acc; acc += sm.pre.hist[b];
            }
        }
        __syncthreads();
        if (tid < 16 && sm.pre.hist[tid] > 0)
            sm.pre.gbase[tid] = atomicAdd(&bcnt[tid], sm.pre.hist[tid]);
        for (int i = tid; i < SUBTOT; i += 256) {
            int v = sm.pre.h2[i];
            if (v > 0) atomicAdd(&cnt2[i], v);
        }
        for (int i = tid; i < cnt; i += 256) {
            int d = dst[c0 + i];
            int s = src[c0 + i];
            int b = d >> NPB_SHIFT;
            unsigned packed = (unsigned)s | ((unsigned)(d & (NPB - 1)) << 17);
            int p = atomicAdd(&sm.pre.hcur[b], 1);
            sm.pre.lout[p] = packed;
            sm.pre.lb[p] = (unsigned char)b;
        }
        __syncthreads();
        for (int i = tid; i < cnt; i += 256) {
            int b = sm.pre.lb[i];
            st_agent_u(&binned[(size_t)b * cap + sm.pre.gbase[b] + (i - sm.pre.hexcl[b])],
                       sm.pre.lout[i]);
        }
        __syncthreads();
    }
    for (int i = blockIdx.x * 256 + tid; i < n4; i += gridDim.x * 256) {
        float4 v = ((const float4*)x)[i];
        ushort4 b;
        b.x = f2bf(v.x); b.y = f2bf(v.y); b.z = f2bf(v.z); b.w = f2bf(v.w);
        ((ushort4*)xb)[i] = b;  // consumed by k_agg (kernel boundary) -> plain
    }
    gbar(&ctrs[0], gridDim.x);

    // ---- phase 1: block 0 scans cnt2 (256 threads x 4 each) ----
    if (blockIdx.x == 0) {
        int vals[4];
        int tot = 0;
#pragma unroll
        for (int k = 0; k < 4; k++) {
            int idx = tid * 4 + k;
            int v = (idx < SUBTOT) ? cnt2[idx] : 0;
            vals[k] = v;
            tot += v;
        }
        sm.scan.part[tid] = tot;
        __syncthreads();
        for (int off = 1; off < 256; off <<= 1) {
            int add = (tid >= off) ? sm.scan.part[tid - off] : 0;
            __syncthreads();
            sm.scan.part[tid] += add;
            __syncthreads();
        }
        int run = sm.scan.part[tid] - tot;  // exclusive base
#pragma unroll
        for (int k = 0; k < 4; k++) {
            int idx = tid * 4 + k;
            if (idx < SUBTOT) { st_agent_i(&sbase[idx], run); st_agent_i(&scur[idx], run); }
            run += vals[k];
        }
        if (tid == 0) st_agent_i(&sbase[SUBTOT], E);
        if (tid < 128)
            __hip_atomic_store(&stats[tid], 0.f, __ATOMIC_RELAXED, __HIP_MEMORY_SCOPE_AGENT);
    }
    gbar(&ctrs[1], gridDim.x);

    // ---- phase 2: sub sort, 64 blocks per coarse bucket ----
    {
        int b = blockIdx.x >> 6;
        int r = blockIdx.x & 63;
        if (b < B) {
            int bs0 = sbase[b << 6];
            int total = sbase[(b + 1) << 6] - bs0;
            const unsigned* bb = binned + (size_t)b * cap;
            for (int c0 = r * 4096; c0 < total; c0 += 64 * 4096) {
                int cnt = min(4096, total - c0);
                if (tid < 64) sm.sub.hist[tid] = 0;
                __syncthreads();
                for (int i = tid; i < cnt; i += 256)
                    atomicAdd(&sm.sub.hist[(bb[c0 + i] >> 24) & 63], 1);
                __syncthreads();
                if (tid == 0) {
                    int acc = 0;
                    for (int f = 0; f < 64; f++) {
                        sm.sub.hexcl[f] = acc; sm.sub.hcur[f] = acc; acc += sm.sub.hist[f];
                    }
                }
                __syncthreads();
                if (tid < 64 && sm.sub.hist[tid] > 0)
                    sm.sub.gbase[tid] = atomicAdd(&scur[(b << 6) + tid], sm.sub.hist[tid]);
                for (int i = tid; i < cnt; i += 256) {
                    unsigned e = bb[c0 + i];
                    int f = (e >> 24) & 63;
                    unsigned rp = (e & 0x1FFFFu) | (((e >> 17) & 127u) << 17);
                    int p = atomicAdd(&sm.sub.hcur[f], 1);
                    sm.sub.lout[p] = rp;
                    sm.sub.lb[p] = (unsigned char)f;
                }
                __syncthreads();
                for (int i = tid; i < cnt; i += 256) {
                    int f = sm.sub.lb[i];
                    st_agent_u(&sorted2[sm.sub.gbase[f] + (i - sm.sub.hexcl[f])],
                               sm.sub.lout[i]);
                }
                __syncthreads();
            }
        }
    }
    gbar(&ctrs[2], gridDim.x);

    // ---- phase 3: csr + deg/dinv/offs, 1 block per sub-bucket ----
    {
        int s = blockIdx.x;
        if (s < SUBTOT) {
            int j0 = sbase[s], j1 = sbase[s + 1];
            if (tid < 128) { sm.csr.hist[tid] = 0; sm.csr.lcur[tid] = 0; }
            __syncthreads();
            for (int j = j0 + tid; j < j1; j += 256)
                atomicAdd(&sm.csr.hist[sorted2[j] >> 17], 1);
            __syncthreads();
            if (tid == 0) {
                int acc = 0;
                for (int k = 0; k < 128; k++) { sm.csr.lbase[k] = acc; acc += sm.csr.hist[k]; }
            }
            __syncthreads();
            if (tid < 128) {  // outputs consumed by k_agg (boundary) -> plain
                int n = (s << 7) + tid;
                if (n < N) {
                    int d = sm.csr.hist[tid];
                    deg[n] = d;
                    dinv[n] = rsqrtf((float)(d + 1));  // +1 = self-loop
                    offs[n] = j0 + sm.csr.lbase[tid];
                }
            }
            for (int j = j0 + tid; j < j1; j += 256) {
                unsigned e = sorted2[j];
                int ld = e >> 17;
                int pos = j0 + sm.csr.lbase[ld] + atomicAdd(&sm.csr.lcur[ld], 1);
                csr[pos] = (int)(e & 0x1FFFFu);  // private window, plain (L2-merge)
            }
        }
    }
}

// Wave per node. lane = (half h, channel-pair p): one 4B load = 2 channels of
// one of 2 edges -> 2 edges per load instruction. Halves combined at the end.
__global__ __launch_bounds__(256) void k_agg(const int* __restrict__ offs,
                                             const int* __restrict__ deg,
                                             const int* __restrict__ csr,
                                             const unsigned short* __restrict__ xb,
                                             const float* __restrict__ dinv,
                                             unsigned* __restrict__ aggb32, int N) {
    int lane = threadIdx.x & 63;
    int p = lane & 31;   // channel pair (channels 2p, 2p+1)
    int h = lane >> 5;   // half: which edge of a pair this lane gathers
    int wid = (blockIdx.x * 256 + threadIdx.x) >> 6;
    int nw = (gridDim.x * 256) >> 6;

    for (int n = wid; n < N; n += nw) {
        float dn = dinv[n];
        unsigned sv = *(const unsigned*)(xb + (size_t)n * 64 + 2 * p);
        float wself = (h == 0) ? dn : 0.f;  // self-loop counted once
        float accx = bf2f(sv & 0xFFFFu) * wself;
        float accy = bf2f(sv >> 16) * wself;
        int j0 = offs[n];
        int j1 = j0 + deg[n];
        for (int jb = j0; jb < j1; jb += 64) {
            int cnt = min(64, j1 - jb);
            int idx = 0;
            float w = 0.f;
            if (lane < cnt) {
                idx = csr[jb + lane];
                w = dinv[idx];
            }
            int j = 0;
            for (; j + 8 <= cnt; j += 8) {
                int s0 = __shfl(idx, j + 0 + h), s1 = __shfl(idx, j + 2 + h);
                int s2 = __shfl(idx, j + 4 + h), s3 = __shfl(idx, j + 6 + h);
                float w0 = __shfl(w, j + 0 + h), w1 = __shfl(w, j + 2 + h);
                float w2 = __shfl(w, j + 4 + h), w3 = __shfl(w, j + 6 + h);
                unsigned v0 = *(const unsigned*)(xb + (size_t)s0 * 64 + 2 * p);
                unsigned v1 = *(const unsigned*)(xb + (size_t)s1 * 64 + 2 * p);
                unsigned v2 = *(const unsigned*)(xb + (size_t)s2 * 64 + 2 * p);
                unsigned v3 = *(const unsigned*)(xb + (size_t)s3 * 64 + 2 * p);
                accx = fmaf(w0, bf2f(v0 & 0xFFFFu), accx);
                accy = fmaf(w0, bf2f(v0 >> 16), accy);
                accx = fmaf(w1, bf2f(v1 & 0xFFFFu), accx);
                accy = fmaf(w1, bf2f(v1 >> 16), accy);
                accx = fmaf(w2, bf2f(v2 & 0xFFFFu), accx);
                accy = fmaf(w2, bf2f(v2 >> 16), accy);
                accx = fmaf(w3, bf2f(v3 & 0xFFFFu), accx);
                accy = fmaf(w3, bf2f(v3 >> 16), accy);
            }
            for (; j + 2 <= cnt; j += 2) {
                int s0 = __shfl(idx, j + h);
                float w0 = __shfl(w, j + h);
                unsigned v0 = *(const unsigned*)(xb + (size_t)s0 * 64 + 2 * p);
                accx = fmaf(w0, bf2f(v0 & 0xFFFFu), accx);
                accy = fmaf(w0, bf2f(v0 >> 16), accy);
            }
            if (j < cnt) {  // odd tail: half 0 contributes, half 1 gets w=0
                int s0 = __shfl(idx, j);
                float w0 = __shfl(w, j);
                if (h) w0 = 0.f;
                unsigned v0 = *(const unsigned*)(xb + (size_t)s0 * 64 + 2 * p);
                accx = fmaf(w0, bf2f(v0 & 0xFFFFu), accx);
                accy = fmaf(w0, bf2f(v0 >> 16), accy);
            }
        }
        accx += __shfl_xor(accx, 32);
        accy += __shfl_xor(accy, 32);
        if (h == 0) {
            unsigned o = (unsigned)f2bf(accx * dn) | ((unsigned)f2bf(accy * dn) << 16);
            aggb32[(size_t)n * 32 + p] = o;
        }
    }
}

// Fused tail: stage tile once; stats (gemm, no stores) -> grid barrier ->
// derive scale/shift -> output gemm from the SAME tile; full-line stores.
__global__ __launch_bounds__(256) void k_tail(const unsigned* __restrict__ aggb32,
                                              const float* __restrict__ W,
                                              float* stats,
                                              const float* __restrict__ gamma,
                                              const float* __restrict__ beta,
                                              float* __restrict__ out,
                                              int* ctr, int N, float invN, int nb) {
    __shared__ unsigned tile[8192];           // 256 rows x 64 bf16
    __shared__ union { float red[512]; float ssl[128]; } u;
    int t = threadIdx.x;
    int lane = t & 63;
    int w = t >> 6;
    int r0 = blockIdx.x * 256;
    const uint4* gp = (const uint4*)(aggb32 + (size_t)r0 * 32);
#pragma unroll
    for (int i = 0; i < 8; i++) {
        int idx = t + 256 * i;
        int n = r0 + (idx >> 3);
        uint4 v = {0u, 0u, 0u, 0u};
        if (n < N) v = gp[idx];
        *(uint4*)(tile + idx * 4) = v;
    }
    float wcol[64];
#pragma unroll
    for (int k = 0; k < 64; k++) wcol[k] = W[k * 64 + lane];
    __syncthreads();

    float psum = 0.f, psq = 0.f;
    for (int rr = 0; rr < 64; rr += 2) {
        int lr0 = w * 64 + rr;
        int n0 = r0 + lr0;
        if (n0 >= N) break;
        const unsigned* row0 = tile + lr0 * 32;
        const unsigned* row1 = row0 + 32;
        float o0 = 0.f, o1 = 0.f;
#pragma unroll
        for (int kp = 0; kp < 32; kp++) {
            unsigned u0 = row0[kp], u1 = row1[kp];
            o0 = fmaf(bf2f(u0 & 0xFFFFu), wcol[2 * kp], o0);
            o0 = fmaf(bf2f(u0 >> 16), wcol[2 * kp + 1], o0);
            o1 = fmaf(bf2f(u1 & 0xFFFFu), wcol[2 * kp], o1);
            o1 = fmaf(bf2f(u1 >> 16), wcol[2 * kp + 1], o1);
        }
        psum += o0;
        psq = fmaf(o0, o0, psq);
        if (n0 + 1 < N) {
            psum += o1;
            psq = fmaf(o1, o1, psq);
        }
    }
    u.red[w * 64 + lane] = psum;
    u.red[256 + w * 64 + lane] = psq;
    __syncthreads();
    if (w == 0) {
        float s = u.red[lane] + u.red[64 + lane] + u.red[128 + lane] + u.red[192 + lane];
        atomicAdd(&stats[lane], s);
    } else if (w == 1) {
        float q = u.red[256 + lane] + u.red[320 + lane] + u.red[384 + lane] + u.red[448 + lane];
        atomicAdd(&stats[64 + lane], q);
    }

    gbar(ctr, nb);  // all blocks' stats atomics complete past this point

    if (t < 64) {
        float s0 = __hip_atomic_load(&stats[t], __ATOMIC_RELAXED, __HIP_MEMORY_SCOPE_AGENT);
        float q0 = __hip_atomic_load(&stats[64 + t], __ATOMIC_RELAXED, __HIP_MEMORY_SCOPE_AGENT);
        float mean = s0 * invN;
        float var = q0 * invN - mean * mean;  // biased var, matches ref
        float sc = gamma[t] * rsqrtf(var + BN_EPS);
        u.ssl[t] = sc;
        u.ssl[64 + t] = beta[t] - mean * sc;
    }
    __syncthreads();
    float sc = u.ssl[lane], sh = u.ssl[64 + lane];

    for (int rr = 0; rr < 64; rr += 2) {
        int lr0 = w * 64 + rr;
        int n0 = r0 + lr0;
        if (n0 >= N) break;
        const unsigned* row0 = tile + lr0 * 32;
        const unsigned* row1 = row0 + 32;
        float o0 = 0.f, o1 = 0.f;
#pragma unroll
        for (int kp = 0; kp < 32; kp++) {
            unsigned u0 = row0[kp], u1 = row1[kp];
            o0 = fmaf(bf2f(u0 & 0xFFFFu), wcol[2 * kp], o0);
            o0 = fmaf(bf2f(u0 >> 16), wcol[2 * kp + 1], o0);
            o1 = fmaf(bf2f(u1 & 0xFFFFu), wcol[2 * kp], o1);
            o1 = fmaf(bf2f(u1 >> 16), wcol[2 * kp + 1], o1);
        }
        o0 = fmaxf(fmaf(o0, sc, sh), 0.f);
        o1 = fmaxf(fmaf(o1, sc, sh), 0.f);
        out[(size_t)n0 * 64 + lane] = o0;
        if (n0 + 1 < N) out[(size_t)(n0 + 1) * 64 + lane] = o1;
    }
}

extern "C" void kernel_launch(void* const* d_in, const int* in_sizes, int n_in,
                              void* d_out, int out_size, void* d_ws, size_t ws_size,
                              hipStream_t stream) {
    const float* x = (const float*)d_in[0];
    const int* ei = (const int*)d_in[1];
    const float* W = (const float*)d_in[2];
    // d_in[3] = bias: cancels inside BatchNorm, unused.
    const float* gamma = (const float*)d_in[4];
    const float* beta = (const float*)d_in[5];
    float* out = (float*)d_out;

    const int N = in_sizes[0] / 64;
    const int E = in_sizes[1] / 2;
    const int* src = ei;
    const int* dst = ei + E;
    const int NB = (N + 255) / 256;             // 391
    const int B = (N + NPB - 1) >> NPB_SHIFT;   // 13 coarse buckets
    const int SUBTOT = B * 64;                  // 832 sub-buckets
    // Slack capacity per coarse bucket: mean count ~131K, sigma ~350.
    // E/12 + 16384 ~= mean + 53 sigma -> overflow impossible.
    const int cap = E / 12 + 16384;

    char* ws = (char*)d_ws;
    size_t o = 0;
    int* ctrs = (int*)(ws + o); o += 64;             // barrier counters (4 used)
    int* cnt2 = (int*)(ws + o); o += 4096;           // 832 ints used
    int* bcnt = (int*)(ws + o); o += 64;             // 13 coarse cursors
    size_t zspan = o;                                // memset: ctrs+cnt2+bcnt
    float* stats = (float*)(ws + o); o += 512;       // zeroed in build ph1
    int* sbase = (int*)(ws + o); o += 3584;          // SUBTOT+1 ints
    int* scur = (int*)(ws + o); o += 3584;
    int* deg = (int*)(ws + o); o += (size_t)4 * N;
    int* offs = (int*)(ws + o); o += (size_t)4 * N;
    float* dinv = (float*)(ws + o); o += (size_t)4 * N;
    unsigned short* xb = (unsigned short*)(ws + o); o += (size_t)128 * N;
    unsigned* aggb32 = (unsigned*)(ws + o); o += (size_t)128 * N;
    unsigned* binned = (unsigned*)(ws + o); o += (size_t)4 * B * cap;
    unsigned* sorted2 = (unsigned*)(ws + o); o += (size_t)4 * E;
    int* csr = (int*)binned;  // alias: binned consumed in ph2 before ph3 writes

    hipMemsetAsync(ws, 0, zspan, stream);

    int n4 = N * 16;
    k_build<<<BUILD_GRID, 256, 0, stream>>>(x, src, dst, xb, cnt2, bcnt, binned,
                                            sbase, scur, stats, deg, dinv, offs,
                                            csr, sorted2, ctrs, E, n4, SUBTOT,
                                            cap, B, N);
    k_agg<<<2048, 256, 0, stream>>>(offs, deg, csr, xb, dinv, aggb32, N);
    k_tail<<<NB, 256, 0, stream>>>(aggb32, W, stats, gamma, beta, out, &ctrs[3],
                                   N, 1.0f / (float)N, NB);
}

// Round 13
// 253.797 us; speedup vs baseline: 2.4807x; 2.4807x over previous
//
#include <hip/hip_runtime.h>
#include <hip/hip_bf16.h>

#ifndef BN_EPS
#define BN_EPS 1e-5f
#endif

// ---------------------------------------------------------------------------
// N=100000, C=64, E=1600000.
// R13 = R11 build pipeline (separate kernels, plain stores, kernel-boundary
// coherence — R12 lesson: intra-kernel agent-scope (sc1) stores for cross-XCD
// visibility cost 440us vs ~40us of dispatch overhead saved) + ONE safe
// fusion: k_tail = gemm1 -> grid barrier -> gemm2, sharing the LDS tile and
// W-column registers (only cross-barrier data = 128 floats of stats via
// ordinary device atomics, proven fast in R11).
// Pipeline: memset -> pre(bin+hist+bf16) -> scanSub -> sub -> csr
//           -> agg -> tail. 7 graph nodes.
// bias cancels inside BatchNorm, skipped.
// ---------------------------------------------------------------------------

#define NPB 8192
#define NPB_SHIFT 13

__device__ __forceinline__ unsigned short f2bf(float f) {
    unsigned u = __float_as_uint(f);
    u += 0x7FFF + ((u >> 16) & 1);  // round-to-nearest-even
    return (unsigned short)(u >> 16);
}
__device__ __forceinline__ float bf2f(unsigned v) {
    return __uint_as_float(v << 16);
}

// Fused: coarse 13-bucket LDS chunk-sort (slack-capacity regions, cursor in
// bcnt) + 832-subbucket histogram (cnt2) + x->bf16.
__global__ __launch_bounds__(256) void k_pre(const float* __restrict__ x,
                                             const int* __restrict__ src,
                                             const int* __restrict__ dst,
                                             unsigned short* __restrict__ xb,
                                             int* __restrict__ cnt2,
                                             int* __restrict__ bcnt,
                                             unsigned* __restrict__ binned,
                                             int E, int n4, int SUBTOT, int cap) {
    __shared__ int hist[16], hexcl[16], hcur[16], gbase[16];
    __shared__ int h2[1024];
    __shared__ unsigned lout[4096];
    __shared__ unsigned char lb[4096];
    int tid = threadIdx.x;
    int c0 = blockIdx.x * 4096;
    if (c0 < E) {  // block-uniform branch
        int cnt = min(4096, E - c0);
        if (tid < 16) hist[tid] = 0;
        for (int i = tid; i < SUBTOT; i += 256) h2[i] = 0;
        __syncthreads();
        for (int i = tid; i < cnt; i += 256) {
            int d = dst[c0 + i];
            atomicAdd(&hist[d >> NPB_SHIFT], 1);
            atomicAdd(&h2[d >> 7], 1);
        }
        __syncthreads();
        if (tid == 0) {
            int acc = 0;
            for (int b = 0; b < 16; b++) { hexcl[b] = acc; hcur[b] = acc; acc += hist[b]; }
        }
        __syncthreads();
        if (tid < 16 && hist[tid] > 0) gbase[tid] = atomicAdd(&bcnt[tid], hist[tid]);
        for (int i = tid; i < SUBTOT; i += 256) {
            int v = h2[i];
            if (v > 0) atomicAdd(&cnt2[i], v);
        }
        for (int i = tid; i < cnt; i += 256) {
            int d = dst[c0 + i];
            int s = src[c0 + i];
            int b = d >> NPB_SHIFT;
            unsigned packed = (unsigned)s | ((unsigned)(d & (NPB - 1)) << 17);
            int p = atomicAdd(&hcur[b], 1);
            lout[p] = packed;
            lb[p] = (unsigned char)b;
        }
        __syncthreads();
        for (int i = tid; i < cnt; i += 256) {
            int b = lb[i];
            binned[(size_t)b * cap + gbase[b] + (i - hexcl[b])] = lout[i];
        }
    }
    int i = blockIdx.x * 256 + tid;
    if (i < n4) {
        float4 v = ((const float4*)x)[i];
        ushort4 b;
        b.x = f2bf(v.x); b.y = f2bf(v.y); b.z = f2bf(v.z); b.w = f2bf(v.w);
        ((ushort4*)xb)[i] = b;
    }
}

// Exact scan of cnt2 -> sbase (excl, +sentinel), scur copy; also zeroes stats.
__global__ __launch_bounds__(1024) void k_scanSub(const int* __restrict__ cnt2,
                                                  int* __restrict__ sbase,
                                                  int* __restrict__ scur,
                                                  float* __restrict__ stats,
                                                  int SUBTOT, int E) {
    __shared__ int s[1024];
    int t = threadIdx.x;
    if (t < 128) stats[t] = 0.f;
    int v = (t < SUBTOT) ? cnt2[t] : 0;
    s[t] = v;
    __syncthreads();
    for (int off = 1; off < 1024; off <<= 1) {
        int add = (t >= off) ? s[t - off] : 0;
        __syncthreads();
        s[t] += add;
        __syncthreads();
    }
    if (t < SUBTOT) {
        int excl = s[t] - v;
        sbase[t] = excl;
        scur[t] = excl;
    }
    if (t == 0) sbase[SUBTOT] = E;
}

// Per coarse bucket (32 blocks each): chunk-sort into 64 sub-buckets at exact
// scur offsets. in: binned region [b*cap, ...). out: src | local7<<17.
__global__ __launch_bounds__(256) void k_sub(const unsigned* __restrict__ binned,
                                             const int* __restrict__ sbase,
                                             int* __restrict__ scur,
                                             unsigned* __restrict__ sorted2,
                                             int cap, int B) {
    __shared__ int hist[64], hexcl[64], hcur[64], gbase[64];
    __shared__ unsigned lout[4096];
    __shared__ unsigned char lb[4096];
    int b = blockIdx.x >> 5;
    int r = blockIdx.x & 31;
    if (b >= B) return;
    int tid = threadIdx.x;
    int total = sbase[(b + 1) << 6] - sbase[b << 6];
    const unsigned* bb = binned + (size_t)b * cap;
    for (int c0 = r * 4096; c0 < total; c0 += 32 * 4096) {
        int cnt = min(4096, total - c0);
        if (tid < 64) hist[tid] = 0;
        __syncthreads();
        for (int i = tid; i < cnt; i += 256)
            atomicAdd(&hist[(bb[c0 + i] >> 24) & 63], 1);  // local13>>7
        __syncthreads();
        if (tid == 0) {
            int acc = 0;
            for (int f = 0; f < 64; f++) { hexcl[f] = acc; hcur[f] = acc; acc += hist[f]; }
        }
        __syncthreads();
        if (tid < 64 && hist[tid] > 0)
            gbase[tid] = atomicAdd(&scur[(b << 6) + tid], hist[tid]);
        for (int i = tid; i < cnt; i += 256) {
            unsigned e = bb[c0 + i];
            int f = (e >> 24) & 63;
            unsigned rp = (e & 0x1FFFFu) | (((e >> 17) & 127u) << 17);
            int p = atomicAdd(&hcur[f], 1);
            lout[p] = rp;
            lb[p] = (unsigned char)f;
        }
        __syncthreads();
        for (int i = tid; i < cnt; i += 256) {
            int f = lb[i];
            sorted2[gbase[f] + (i - hexcl[f])] = lout[i];
        }
        __syncthreads();
    }
}

// One block per 128-node sub-bucket: private csr window scatter (single CU ->
// L2 merges) + deg/dinv/offs from the LDS histogram (coalesced 512B stores).
__global__ __launch_bounds__(256) void k_csr(const unsigned* __restrict__ sorted2,
                                             const int* __restrict__ sbase,
                                             int* __restrict__ deg,
                                             float* __restrict__ dinv,
                                             int* __restrict__ offs,
                                             int* __restrict__ csr, int N) {
    __shared__ int hist[128], lbase[128], lcur[128];
    int s = blockIdx.x;
    int j0 = sbase[s], j1 = sbase[s + 1];
    int tid = threadIdx.x;
    if (tid < 128) { hist[tid] = 0; lcur[tid] = 0; }
    __syncthreads();
    for (int j = j0 + tid; j < j1; j += 256)
        atomicAdd(&hist[sorted2[j] >> 17], 1);
    __syncthreads();
    if (tid == 0) {
        int acc = 0;
        for (int k = 0; k < 128; k++) { lbase[k] = acc; acc += hist[k]; }
    }
    __syncthreads();
    if (tid < 128) {  // deg / dinv / offs for this sub-bucket's 128 nodes
        int n = (s << 7) + tid;
        if (n < N) {
            int d = hist[tid];
            deg[n] = d;
            dinv[n] = rsqrtf((float)(d + 1));  // +1 = self-loop
            offs[n] = j0 + lbase[tid];         // csr is globally dst-ordered
        }
    }
    for (int j = j0 + tid; j < j1; j += 256) {
        unsigned e = sorted2[j];
        int ld = e >> 17;
        int pos = j0 + lbase[ld] + atomicAdd(&lcur[ld], 1);
        csr[pos] = (int)(e & 0x1FFFFu);
    }
}

// Wave per node. lane = (half h, channel-pair p): one 4B load = 2 channels of
// one of 2 edges -> 2 edges per load instruction. Halves combined at the end.
__global__ __launch_bounds__(256) void k_agg(const int* __restrict__ offs,
                                             const int* __restrict__ deg,
                                             const int* __restrict__ csr,
                                             const unsigned short* __restrict__ xb,
                                             const float* __restrict__ dinv,
                                             unsigned* __restrict__ aggb32, int N) {
    int lane = threadIdx.x & 63;
    int p = lane & 31;   // channel pair (channels 2p, 2p+1)
    int h = lane >> 5;   // half: which edge of a pair this lane gathers
    int wid = (blockIdx.x * 256 + threadIdx.x) >> 6;
    int nw = (gridDim.x * 256) >> 6;

    for (int n = wid; n < N; n += nw) {
        float dn = dinv[n];
        unsigned sv = *(const unsigned*)(xb + (size_t)n * 64 + 2 * p);
        float wself = (h == 0) ? dn : 0.f;  // self-loop counted once
        float accx = bf2f(sv & 0xFFFFu) * wself;
        float accy = bf2f(sv >> 16) * wself;
        int j0 = offs[n];
        int j1 = j0 + deg[n];
        for (int jb = j0; jb < j1; jb += 64) {
            int cnt = min(64, j1 - jb);
            int idx = 0;
            float w = 0.f;
            if (lane < cnt) {
                idx = csr[jb + lane];
                w = dinv[idx];
            }
            int j = 0;
            for (; j + 8 <= cnt; j += 8) {
                int s0 = __shfl(idx, j + 0 + h), s1 = __shfl(idx, j + 2 + h);
                int s2 = __shfl(idx, j + 4 + h), s3 = __shfl(idx, j + 6 + h);
                float w0 = __shfl(w, j + 0 + h), w1 = __shfl(w, j + 2 + h);
                float w2 = __shfl(w, j + 4 + h), w3 = __shfl(w, j + 6 + h);
                unsigned v0 = *(const unsigned*)(xb + (size_t)s0 * 64 + 2 * p);
                unsigned v1 = *(const unsigned*)(xb + (size_t)s1 * 64 + 2 * p);
                unsigned v2 = *(const unsigned*)(xb + (size_t)s2 * 64 + 2 * p);
                unsigned v3 = *(const unsigned*)(xb + (size_t)s3 * 64 + 2 * p);
                accx = fmaf(w0, bf2f(v0 & 0xFFFFu), accx);
                accy = fmaf(w0, bf2f(v0 >> 16), accy);
                accx = fmaf(w1, bf2f(v1 & 0xFFFFu), accx);
                accy = fmaf(w1, bf2f(v1 >> 16), accy);
                accx = fmaf(w2, bf2f(v2 & 0xFFFFu), accx);
                accy = fmaf(w2, bf2f(v2 >> 16), accy);
                accx = fmaf(w3, bf2f(v3 & 0xFFFFu), accx);
                accy = fmaf(w3, bf2f(v3 >> 16), accy);
            }
            for (; j + 2 <= cnt; j += 2) {
                int s0 = __shfl(idx, j + h);
                float w0 = __shfl(w, j + h);
                unsigned v0 = *(const unsigned*)(xb + (size_t)s0 * 64 + 2 * p);
                accx = fmaf(w0, bf2f(v0 & 0xFFFFu), accx);
                accy = fmaf(w0, bf2f(v0 >> 16), accy);
            }
            if (j < cnt) {  // odd tail: half 0 contributes, half 1 gets w=0
                int s0 = __shfl(idx, j);
                float w0 = __shfl(w, j);
                if (h) w0 = 0.f;
                unsigned v0 = *(const unsigned*)(xb + (size_t)s0 * 64 + 2 * p);
                accx = fmaf(w0, bf2f(v0 & 0xFFFFu), accx);
                accy = fmaf(w0, bf2f(v0 >> 16), accy);
            }
        }
        accx += __shfl_xor(accx, 32);
        accy += __shfl_xor(accy, 32);
        if (h == 0) {
            unsigned o = (unsigned)f2bf(accx * dn) | ((unsigned)f2bf(accy * dn) << 16);
            aggb32[(size_t)n * 32 + p] = o;
        }
    }
}

// Grid barrier (co-resident blocks only). __syncthreads drains vmcnt (prior
// atomics complete) before arrival.
__device__ __forceinline__ void gbar(int* ctr, int nb) {
    __syncthreads();
    if (threadIdx.x == 0) {
        __hip_atomic_fetch_add(ctr, 1, __ATOMIC_ACQ_REL, __HIP_MEMORY_SCOPE_AGENT);
        while (__hip_atomic_load(ctr, __ATOMIC_ACQUIRE, __HIP_MEMORY_SCOPE_AGENT) < nb)
            __builtin_amdgcn_s_sleep(2);
    }
    __syncthreads();
}

// Fused tail: stage tile+W once; stats gemm (no stores, device atomicAdd of
// 128 floats) -> grid barrier -> derive scale/shift -> output gemm from the
// SAME tile; full-line 256B/row stores.
__global__ __launch_bounds__(256) void k_tail(const unsigned* __restrict__ aggb32,
                                              const float* __restrict__ W,
                                              float* stats,
                                              const float* __restrict__ gamma,
                                              const float* __restrict__ beta,
                                              float* __restrict__ out,
                                              int* ctr, int N, float invN, int nb) {
    __shared__ unsigned tile[8192];           // 256 rows x 64 bf16
    __shared__ union { float red[512]; float ssl[128]; } u;
    int t = threadIdx.x;
    int lane = t & 63;
    int w = t >> 6;
    int r0 = blockIdx.x * 256;
    const uint4* gp = (const uint4*)(aggb32 + (size_t)r0 * 32);
#pragma unroll
    for (int i = 0; i < 8; i++) {
        int idx = t + 256 * i;
        int n = r0 + (idx >> 3);
        uint4 v = {0u, 0u, 0u, 0u};
        if (n < N) v = gp[idx];
        *(uint4*)(tile + idx * 4) = v;
    }
    float wcol[64];
#pragma unroll
    for (int k = 0; k < 64; k++) wcol[k] = W[k * 64 + lane];
    __syncthreads();

    float psum = 0.f, psq = 0.f;
    for (int rr = 0; rr < 64; rr += 2) {
        int lr0 = w * 64 + rr;
        int n0 = r0 + lr0;
        if (n0 >= N) break;
        const unsigned* row0 = tile + lr0 * 32;
        const unsigned* row1 = row0 + 32;
        float o0 = 0.f, o1 = 0.f;
#pragma unroll
        for (int kp = 0; kp < 32; kp++) {
            unsigned u0 = row0[kp], u1 = row1[kp];
            o0 = fmaf(bf2f(u0 & 0xFFFFu), wcol[2 * kp], o0);
            o0 = fmaf(bf2f(u0 >> 16), wcol[2 * kp + 1], o0);
            o1 = fmaf(bf2f(u1 & 0xFFFFu), wcol[2 * kp], o1);
            o1 = fmaf(bf2f(u1 >> 16), wcol[2 * kp + 1], o1);
        }
        psum += o0;
        psq = fmaf(o0, o0, psq);
        if (n0 + 1 < N) {
            psum += o1;
            psq = fmaf(o1, o1, psq);
        }
    }
    u.red[w * 64 + lane] = psum;
    u.red[256 + w * 64 + lane] = psq;
    __syncthreads();
    if (w == 0) {
        float s = u.red[lane] + u.red[64 + lane] + u.red[128 + lane] + u.red[192 + lane];
        atomicAdd(&stats[lane], s);
    } else if (w == 1) {
        float q = u.red[256 + lane] + u.red[320 + lane] + u.red[384 + lane] + u.red[448 + lane];
        atomicAdd(&stats[64 + lane], q);
    }

    gbar(ctr, nb);  // all blocks' stats atomics visible past this point

    if (t < 64) {
        float s0 = __hip_atomic_load(&stats[t], __ATOMIC_RELAXED, __HIP_MEMORY_SCOPE_AGENT);
        float q0 = __hip_atomic_load(&stats[64 + t], __ATOMIC_RELAXED, __HIP_MEMORY_SCOPE_AGENT);
        float mean = s0 * invN;
        float var = q0 * invN - mean * mean;  // biased var, matches ref
        float sc = gamma[t] * rsqrtf(var + BN_EPS);
        u.ssl[t] = sc;
        u.ssl[64 + t] = beta[t] - mean * sc;
    }
    __syncthreads();
    float sc = u.ssl[lane], sh = u.ssl[64 + lane];

    for (int rr = 0; rr < 64; rr += 2) {
        int lr0 = w * 64 + rr;
        int n0 = r0 + lr0;
        if (n0 >= N) break;
        const unsigned* row0 = tile + lr0 * 32;
        const unsigned* row1 = row0 + 32;
        float o0 = 0.f, o1 = 0.f;
#pragma unroll
        for (int kp = 0; kp < 32; kp++) {
            unsigned u0 = row0[kp], u1 = row1[kp];
            o0 = fmaf(bf2f(u0 & 0xFFFFu), wcol[2 * kp], o0);
            o0 = fmaf(bf2f(u0 >> 16), wcol[2 * kp + 1], o0);
            o1 = fmaf(bf2f(u1 & 0xFFFFu), wcol[2 * kp], o1);
            o1 = fmaf(bf2f(u1 >> 16), wcol[2 * kp + 1], o1);
        }
        o0 = fmaxf(fmaf(o0, sc, sh), 0.f);
        o1 = fmaxf(fmaf(o1, sc, sh), 0.f);
        out[(size_t)n0 * 64 + lane] = o0;
        if (n0 + 1 < N) out[(size_t)(n0 + 1) * 64 + lane] = o1;
    }
}

extern "C" void kernel_launch(void* const* d_in, const int* in_sizes, int n_in,
                              void* d_out, int out_size, void* d_ws, size_t ws_size,
                              hipStream_t stream) {
    const float* x = (const float*)d_in[0];
    const int* ei = (const int*)d_in[1];
    const float* W = (const float*)d_in[2];
    // d_in[3] = bias: cancels inside BatchNorm, unused.
    const float* gamma = (const float*)d_in[4];
    const float* beta = (const float*)d_in[5];
    float* out = (float*)d_out;

    const int N = in_sizes[0] / 64;
    const int E = in_sizes[1] / 2;
    const int* src = ei;
    const int* dst = ei + E;
    const int NB = (N + 255) / 256;             // 391
    const int B = (N + NPB - 1) >> NPB_SHIFT;   // 13 coarse buckets
    const int SUBTOT = B * 64;                  // 832 sub-buckets
    // Slack capacity per coarse bucket: mean count ~131K, sigma ~350.
    // E/12 + 16384 ~= mean + 53 sigma -> overflow impossible.
    const int cap = E / 12 + 16384;

    char* ws = (char*)d_ws;
    size_t o = 0;
    int* ctr = (int*)(ws + o); o += 64;              // tail barrier counter
    int* cnt2 = (int*)(ws + o); o += 4096;           // 832 ints used
    int* bcnt = (int*)(ws + o); o += 64;             // 13 coarse cursors
    size_t zspan = o;                                // memset: ctr+cnt2+bcnt
    float* stats = (float*)(ws + o); o += 512;       // zeroed in k_scanSub
    int* sbase = (int*)(ws + o); o += 3584;          // SUBTOT+1 ints
    int* scur = (int*)(ws + o); o += 3584;
    int* deg = (int*)(ws + o); o += (size_t)4 * N;
    int* offs = (int*)(ws + o); o += (size_t)4 * N;
    float* dinv = (float*)(ws + o); o += (size_t)4 * N;
    unsigned short* xb = (unsigned short*)(ws + o); o += (size_t)128 * N;
    unsigned* aggb32 = (unsigned*)(ws + o); o += (size_t)128 * N;
    unsigned* binned = (unsigned*)(ws + o); o += (size_t)4 * B * cap;
    unsigned* sorted2 = (unsigned*)(ws + o); o += (size_t)4 * E;
    int* csr = (int*)binned;  // alias: binned consumed by k_sub before k_csr

    hipMemsetAsync(ws, 0, zspan, stream);

    int n4 = N * 16;
    int preBlocks = ((n4 + 255) / 256 > (E + 4095) / 4096) ? (n4 + 255) / 256
                                                           : (E + 4095) / 4096;
    k_pre<<<preBlocks, 256, 0, stream>>>(x, src, dst, xb, cnt2, bcnt, binned,
                                         E, n4, SUBTOT, cap);
    k_scanSub<<<1, 1024, 0, stream>>>(cnt2, sbase, scur, stats, SUBTOT, E);
    k_sub<<<B * 32, 256, 0, stream>>>(binned, sbase, scur, sorted2, cap, B);
    k_csr<<<SUBTOT, 256, 0, stream>>>(sorted2, sbase, deg, dinv, offs, csr, N);
    k_agg<<<2048, 256, 0, stream>>>(offs, deg, csr, xb, dinv, aggb32, N);
    k_tail<<<NB, 256, 0, stream>>>(aggb32, W, stats, gamma, beta, out, ctr,
                                   N, 1.0f / (float)N, NB);
}